// Round 15
// baseline (1303.763 us; speedup 1.0000x reference)
//
#include <hip/hip_runtime.h>

// QuantizedLinear: out[b,s,o] = sum_k x[b,s,k] * qw[o,k]
// qw = Wint/(9*alpha), Wint in {-2..2}  -> INT8 MFMA GEMM:
//   x quantized per-row to i8 (s_m = rowmax/127), W exact in i8,
//   i32 accumulation exact; epilogue scales by s_m/(9*alpha).
// M=16384, N=4096, K=4096. fp32 in/out.
//
// R15: clean SIMD-mate anti-phase test. R8 verbatim (all per-phase
//   lgkm0+SBAR gates, triple-A + double-B 80 KiB, positional staging,
//   vmcnt(2) tile ledger, 0-conflict swizzle) + ONE change: wm=1 waves
//   (SIMD-mates of wm=0) run the tile's 4 phases in order [2,3,0,1].
//   Legal: all tile-t reads come from buffers landed at the tile-start
//   barrier (end-of-t-1 vmcnt(2) leaves only A(t+1) in flight), so
//   intra-tile phase order is free; stages stay positional in BOTH
//   branches -> identical per-wave vmcnt semantics. Mechanism: half the
//   CU's waves read while the other half MFMA -> LDS port and matrix
//   pipe alternate-fed instead of lockstep burst-sum (R5 drift failed
//   because identical programs stay locked; R6's swap was spoiled by
//   gate removal -> spill).
// Prepass: fused X+W quant (R12), chunked+swizzled images.

typedef unsigned short u16;
typedef unsigned int u32;
typedef signed char s8;
typedef int v4i __attribute__((ext_vector_type(4)));

#define MDIM 16384
#define NDIM 4096
#define KDIM 4096

// ---------- helpers ----------

__device__ __forceinline__ float quant_wint(float w, float alpha) {
  // nearest of {3.5,4.0,4.5,5.0,5.5} to 4.5*(1+w*alpha); argmin tie -> lower level.
  float tv = 4.5f * (1.0f + w * alpha);
  float u = (tv - 3.5f) * 2.0f;
  float f = ceilf(u - 0.5f);
  f = fminf(fmaxf(f, 0.0f), 4.0f);
  return f - 2.0f;                  // Wint in {-2..2}; scale 1/(9*alpha) in epilogue
}

__device__ __forceinline__ void gld16(const void* g, void* l) {
  __builtin_amdgcn_global_load_lds(
      (const __attribute__((address_space(1))) void*)g,
      (__attribute__((address_space(3))) void*)l, 16, 0, 0);
}

__device__ __forceinline__ int q8(float x, float sinv) {
  float f = rintf(x * sinv);
  f = fminf(fmaxf(f, -127.0f), 127.0f);
  return (int)f;
}

// ---------- fused prepass: X rows then W rows, chunked+swizzled images ----------
// chunk(rowblk256,kblk64) = 16384B; image[r*64 + (c ^ (((r>>1)&3)<<4))]

__global__ __launch_bounds__(256) void quant_xw_kernel(
    const float4* __restrict__ X, const float4* __restrict__ W,
    const float* __restrict__ pAlpha,
    s8* __restrict__ Xq, s8* __restrict__ Wq, float* __restrict__ scales) {
  const int b = blockIdx.x;
  const int t = threadIdx.x;
  if (b < MDIM) {
    // ---- x row: per-row absmax scale -> i8 ----
    const int m = b;
    const float4* row = X + (size_t)m * 1024;
    float4 v0 = row[t * 4 + 0], v1 = row[t * 4 + 1], v2 = row[t * 4 + 2], v3 = row[t * 4 + 3];
    float vals[16] = {v0.x, v0.y, v0.z, v0.w, v1.x, v1.y, v1.z, v1.w,
                      v2.x, v2.y, v2.z, v2.w, v3.x, v3.y, v3.z, v3.w};
    float mx = 0.0f;
#pragma unroll
    for (int j = 0; j < 16; ++j) mx = fmaxf(mx, fabsf(vals[j]));
#pragma unroll
    for (int s = 1; s < 64; s <<= 1) mx = fmaxf(mx, __shfl_xor(mx, s));
    __shared__ float red[4];
    if ((t & 63) == 0) red[t >> 6] = mx;
    __syncthreads();
    float rmax = fmaxf(fmaxf(red[0], red[1]), fmaxf(red[2], red[3]));
    float sinv = rmax > 0.0f ? 127.0f / rmax : 0.0f;
    if (t == 0) scales[m] = rmax * (1.0f / 127.0f);
    u32 pk[4];
#pragma unroll
    for (int p = 0; p < 4; ++p) {
      u32 w = 0;
#pragma unroll
      for (int j = 0; j < 4; ++j)
        w |= ((u32)(unsigned char)(signed char)q8(vals[p * 4 + j], sinv)) << (8 * j);
      pk[p] = w;
    }
    size_t chunk = ((size_t)(m >> 8) * 64 + (size_t)(t >> 2)) * 16384;
    u32 off = (u32)((m & 255) * 64 + ((((t & 3) ^ ((m >> 1) & 3)) << 4)));
    *(uint4*)(Xq + chunk + off) = make_uint4(pk[0], pk[1], pk[2], pk[3]);
  } else {
    // ---- w row: quantize to Wint in {-2..2} ----
    const float alpha = pAlpha[0];
    const int n = b - MDIM;
    const float4* row = W + (size_t)n * 1024;
    float4 v0 = row[t * 4 + 0], v1 = row[t * 4 + 1], v2 = row[t * 4 + 2], v3 = row[t * 4 + 3];
    float vals[16] = {v0.x, v0.y, v0.z, v0.w, v1.x, v1.y, v1.z, v1.w,
                      v2.x, v2.y, v2.z, v2.w, v3.x, v3.y, v3.z, v3.w};
    u32 pk[4];
#pragma unroll
    for (int p = 0; p < 4; ++p) {
      u32 w = 0;
#pragma unroll
      for (int j = 0; j < 4; ++j) {
        int q = (int)quant_wint(vals[p * 4 + j], alpha);   // -2..2 exact
        w |= ((u32)(unsigned char)(signed char)q) << (8 * j);
      }
      pk[p] = w;
    }
    size_t chunk = ((size_t)(n >> 8) * 64 + (size_t)(t >> 2)) * 16384;
    u32 off = (u32)((n & 255) * 64 + ((((t & 3) ^ ((n >> 1) & 3)) << 4)));
    *(uint4*)(Wq + chunk + off) = make_uint4(pk[0], pk[1], pk[2], pk[3]);
  }
}

// ---------- main GEMM: 256x256, BK=64, i8, anti-phased SIMD-mates ----------

#define BM 256
#define BN 256
#define BK 64
#define NKT (KDIM / BK)   // 64

// LDS byte map: Abuf p (0..2): p*16384 ; Bbuf q (0..1): 49152 + q*16384  = 80 KiB

__global__ __launch_bounds__(512, 2) void qgemm_kernel(
    const s8* __restrict__ Xq, const s8* __restrict__ Wq,
    const float* __restrict__ scales, const float* __restrict__ pAlpha,
    float* __restrict__ out) {
  __shared__ __align__(16) char sm8[81920];

  const int t512 = threadIdx.x;
  const int lane = t512 & 63;
  const int wave = t512 >> 6;
  const int wm = wave >> 2;      // 0..1 == SIMD-mate parity (waves i, i+4 share SIMD i)
  const int wn = wave & 3;       // 0..3

  // XCD-chunked swizzle: nwg=1024, 8 XCDs, 128 per chunk
  const int bid = blockIdx.x;
  const int nid = (bid & 7) * 128 + (bid >> 3);
  const int m_idx = nid >> 4;    // 64 M-tiles
  const int n_idx = nid & 15;    // 16 N-tiles (consecutive nid share A panel)
  const int m0 = m_idx * BM, n0 = n_idx * BN;

  const float alpha = pAlpha[0];

  v4i acc[8][4] = {};
  v4i bfr[4];

  // read byte-offset within a 64B row: k-slot (lane>>4), XOR'd by (row>>1)&3
  // (row = 16*k + (lane&15) -> (row>>1)&3 == (lane>>1)&3)
  const int koff = (((lane >> 4) ^ ((lane >> 1) & 3)) << 4);

#define AROW(MI) (wm * 64 + ((MI) >> 2) * 128 + ((MI)&3) * 16 + (lane & 15))
#define BROW(NJ) (wn * 32 + ((NJ) >> 1) * 128 + ((NJ)&1) * 16 + (lane & 15))
#define LDA(AB, MI) (*(const v4i*)(sm8 + (AB) + AROW(MI) * 64 + koff))
#define LDB(BB, NJ) (*(const v4i*)(sm8 + (BB) + BROW(NJ) * 64 + koff))

  // chunk bases (16 KiB per 256x64 operand tile; KT wraps, junk tail lands
  // only in buffers that are never read again)
#define GAC(KT) (Xq + ((size_t)m_idx * 64 + (size_t)((KT)&63)) * 16384)
#define GBC(KT) (Wq + ((size_t)n_idx * 64 + (size_t)((KT)&63)) * 16384)

  // stage one 8KB sweep (S=0/1) of a 16KB tile: 1 gld16/thread, linear dest
#define STAGE(GC, S, LB) do { \
    const s8* _g = (GC) + (S)*8192 + wave * 1024 + lane * 16; \
    gld16(_g, (void*)(sm8 + (LB) + (S)*8192 + wave * 1024)); \
  } while (0)

#define MFMA8(MI0, MI1, A0, A1) do { \
    acc[MI0][0] = __builtin_amdgcn_mfma_i32_16x16x64_i8(A0, bfr[0], acc[MI0][0], 0, 0, 0); \
    acc[MI0][1] = __builtin_amdgcn_mfma_i32_16x16x64_i8(A0, bfr[1], acc[MI0][1], 0, 0, 0); \
    acc[MI0][2] = __builtin_amdgcn_mfma_i32_16x16x64_i8(A0, bfr[2], acc[MI0][2], 0, 0, 0); \
    acc[MI0][3] = __builtin_amdgcn_mfma_i32_16x16x64_i8(A0, bfr[3], acc[MI0][3], 0, 0, 0); \
    acc[MI1][0] = __builtin_amdgcn_mfma_i32_16x16x64_i8(A1, bfr[0], acc[MI1][0], 0, 0, 0); \
    acc[MI1][1] = __builtin_amdgcn_mfma_i32_16x16x64_i8(A1, bfr[1], acc[MI1][1], 0, 0, 0); \
    acc[MI1][2] = __builtin_amdgcn_mfma_i32_16x16x64_i8(A1, bfr[2], acc[MI1][2], 0, 0, 0); \
    acc[MI1][3] = __builtin_amdgcn_mfma_i32_16x16x64_i8(A1, bfr[3], acc[MI1][3], 0, 0, 0); \
  } while (0)

  // phase: {ds_read 2 A-frags (+4 B-frags in first-executed phase); stage 1
  // sweep} -> lgkm(0) gate (bounds live ranges - R6 lesson) -> 8 MFMA
#define PHASE(AB, MI0, MI1, READB, BB, SGC, SS, SLB) do { \
    if (READB) { \
      bfr[0] = LDB(BB, 0); bfr[1] = LDB(BB, 1); \
      bfr[2] = LDB(BB, 2); bfr[3] = LDB(BB, 3); \
    } \
    v4i a0 = LDA(AB, MI0); \
    v4i a1 = LDA(AB, MI1); \
    STAGE(SGC, SS, SLB); \
    __builtin_amdgcn_sched_barrier(0); \
    asm volatile("s_waitcnt lgkmcnt(0)" ::: "memory"); \
    __builtin_amdgcn_sched_barrier(0); \
    __builtin_amdgcn_s_setprio(1); \
    MFMA8(MI0, MI1, a0, a1); \
    __builtin_amdgcn_s_setprio(0); \
  } while (0)

#define TILEGATE do { \
    __builtin_amdgcn_sched_barrier(0); \
    asm volatile("s_waitcnt vmcnt(2)" ::: "memory"); \
    __builtin_amdgcn_s_barrier(); \
    __builtin_amdgcn_sched_barrier(0); \
  } while (0)

  // one K-tile: 4 phases. wm=0 runs clusters [01][23][45][67]; wm=1 (the
  // SIMD-mates) runs [45][67][01][23] -> at any instant half the waves are
  // in a read-phase while their mates are in an MFMA cluster. All tile-t
  // reads come from buffers landed at the tile-start barrier, so phase
  // order is free. Stages are positional (same issue order both branches):
  // B(t+1)s0, B(t+1)s1, A(t+2)s0, A(t+2)s1 -> vmcnt(2) leaves A(t+2).
#define KTILE(AB, BB, BBN, ASB, TT) do { \
    if (wm == 0) { \
      PHASE(AB, 0, 1, 1, BB, GBC((TT) + 1), 0, BBN); \
      PHASE(AB, 2, 3, 0, BB, GBC((TT) + 1), 1, BBN); \
      PHASE(AB, 4, 5, 0, BB, GAC((TT) + 2), 0, ASB); \
      PHASE(AB, 6, 7, 0, BB, GAC((TT) + 2), 1, ASB); \
    } else { \
      PHASE(AB, 4, 5, 1, BB, GBC((TT) + 1), 0, BBN); \
      PHASE(AB, 6, 7, 0, BB, GBC((TT) + 1), 1, BBN); \
      PHASE(AB, 0, 1, 0, BB, GAC((TT) + 2), 0, ASB); \
      PHASE(AB, 2, 3, 0, BB, GAC((TT) + 2), 1, ASB); \
    } \
    TILEGATE; \
  } while (0)

  // prologue: B(0)->Bbuf0, A(0)->Abuf0, A(1)->Abuf1; vm2 leaves A(1) in flight
  STAGE(GBC(0), 0, 49152);
  STAGE(GBC(0), 1, 49152);
  STAGE(GAC(0), 0, 0);
  STAGE(GAC(0), 1, 0);
  STAGE(GAC(1), 0, 16384);
  STAGE(GAC(1), 1, 16384);
  asm volatile("s_waitcnt vmcnt(2)" ::: "memory");
  __builtin_amdgcn_s_barrier();
  __builtin_amdgcn_sched_barrier(0);

  int aC = 0, aN = 16384, aS = 32768;

#pragma unroll 1
  for (int t = 0; t < NKT; t += 2) {
    // tile t: A in aC, B in Bbuf0; stage B(t+1)->Bbuf1, A(t+2)->aS
    KTILE(aC, 49152, 65536, aS, t);
    // tile t+1: A in aN, B in Bbuf1; stage B(t+2)->Bbuf0, A(t+3)->aC
    KTILE(aN, 65536, 49152, aC, t + 1);
    int tmp = aC; aC = aS; aS = aN; aN = tmp;
  }

  // epilogue: out = acc_i32 * scales[row] / (9*alpha)
  const float inv9a = 1.0f / (9.0f * alpha);
#pragma unroll
  for (int mi = 0; mi < 8; ++mi) {
    int rbase = m0 + (mi >> 2) * 128 + wm * 64 + (mi & 3) * 16 + (lane >> 4) * 4;
    float s0 = scales[rbase + 0] * inv9a;
    float s1 = scales[rbase + 1] * inv9a;
    float s2 = scales[rbase + 2] * inv9a;
    float s3 = scales[rbase + 3] * inv9a;
#pragma unroll
    for (int nj = 0; nj < 4; ++nj) {
      int col = n0 + (nj >> 1) * 128 + wn * 32 + (nj & 1) * 16 + (lane & 15);
      out[(size_t)(rbase + 0) * NDIM + col] = (float)acc[mi][nj][0] * s0;
      out[(size_t)(rbase + 1) * NDIM + col] = (float)acc[mi][nj][1] * s1;
      out[(size_t)(rbase + 2) * NDIM + col] = (float)acc[mi][nj][2] * s2;
      out[(size_t)(rbase + 3) * NDIM + col] = (float)acc[mi][nj][3] * s3;
    }
  }
#undef KTILE
#undef TILEGATE
#undef PHASE
#undef MFMA8
#undef STAGE
#undef GAC
#undef GBC
#undef LDA
#undef LDB
#undef AROW
#undef BROW
}

// ---------- fallback (ws too small): fp32 tiled GEMM, quant on the fly ----------

__global__ void fb_gemm_kernel(const float* __restrict__ X, const float* __restrict__ W,
                               const float* __restrict__ pAlpha, float* __restrict__ out) {
  __shared__ float As[64][17];
  __shared__ float Ws[64][17];
  const float alpha = pAlpha[0];
  const float scale = 1.0f / (9.0f * alpha);
  const int bm = blockIdx.x >> 6, bn = blockIdx.x & 63;
  const int t = threadIdx.x;
  const int tx = t & 15, ty = t >> 4;
  float acc[4][4] = {};
  for (int k0 = 0; k0 < KDIM; k0 += 16) {
    int r = t >> 2;
#pragma unroll
    for (int i = 0; i < 4; ++i) {
      int c = (t & 3) * 4 + i;
      As[r][c] = X[(size_t)(bm * 64 + r) * KDIM + k0 + c];
      float w = W[(size_t)(bn * 64 + r) * KDIM + k0 + c];
      Ws[r][c] = quant_wint(w, alpha) * scale;
    }
    __syncthreads();
#pragma unroll
    for (int kk = 0; kk < 16; ++kk)
#pragma unroll
      for (int i = 0; i < 4; ++i)
#pragma unroll
        for (int j = 0; j < 4; ++j)
          acc[i][j] += As[ty * 4 + i][kk] * Ws[tx * 4 + j][kk];
    __syncthreads();
  }
#pragma unroll
  for (int i = 0; i < 4; ++i)
#pragma unroll
    for (int j = 0; j < 4; ++j)
      out[(size_t)(bm * 64 + ty * 4 + i) * NDIM + bn * 64 + tx * 4 + j] = acc[i][j];
}

// ---------- launch ----------

extern "C" void kernel_launch(void* const* d_in, const int* in_sizes, int n_in,
                              void* d_out, int out_size, void* d_ws, size_t ws_size,
                              hipStream_t stream) {
  const float* x = (const float*)d_in[0];       // [16384,4096]
  const float* w = (const float*)d_in[1];       // [4096,4096]
  const float* alpha = (const float*)d_in[2];   // scalar
  float* out = (float*)d_out;

  const size_t XQ_BYTES = (size_t)MDIM * KDIM;              // 67.1 MB
  const size_t WQ_BYTES = (size_t)NDIM * KDIM;              // 16.8 MB
  const size_t SC_BYTES = (size_t)MDIM * 4;                 // 64 KB
  const size_t NEED = XQ_BYTES + WQ_BYTES + SC_BYTES;       // ~84 MB

  if (ws_size >= NEED) {
    s8* Xq = (s8*)d_ws;
    s8* Wq = (s8*)((char*)d_ws + XQ_BYTES);
    float* scales = (float*)((char*)d_ws + XQ_BYTES + WQ_BYTES);
    quant_xw_kernel<<<MDIM + NDIM, 256, 0, stream>>>(
        (const float4*)x, (const float4*)w, alpha, Xq, Wq, scales);
    qgemm_kernel<<<(MDIM / BM) * (NDIM / BN), 512, 0, stream>>>(
        Xq, Wq, scales, alpha, out);
  } else {
    fb_gemm_kernel<<<(MDIM / 64) * (NDIM / 64), 256, 0, stream>>>(x, w, alpha, out);
  }
}

// Round 16
// 361.588 us; speedup vs baseline: 3.6057x; 3.6057x over previous
//
#include <hip/hip_runtime.h>

// QuantizedLinear: out[b,s,o] = sum_k x[b,s,k] * qw[o,k]
// qw = Wint/(9*alpha), Wint in {-2..2}  -> INT8 MFMA GEMM:
//   x quantized per-row to i8 (s_m = rowmax/127), W exact in i8,
//   i32 accumulation exact; epilogue scales by s_m/(9*alpha).
// M=16384, N=4096, K=4096. fp32 in/out.
//
// R16: REVERT to R12 (verified best: 361.6us total; qgemm 285us, MfmaUtil
//   43%, 0 bank conflicts, no spill). R15's wave-divergent phase order
//   spilled (3rd time: R6, R11, R15) -- hipcc cannot hold acc[8][4] across
//   duplicated gated bodies. Structural plateau of this family:
//   LDS-port burst (~1100-1400 cyc/tile/CU) + MFMA burst (1307) alternate
//   in wave-lockstep and SUM (~2700 cyc/tile = 285us); 9 schedule
//   experiments failed to overlap them (spill / no-engage / worse-trade).
// Structure: 256x256 i8 GEMM, BK=64, quad-A (64KiB) + double-B (32KiB)
//   LDS, cross-tile A-prefetch into regs, per-phase lgkm0+SBAR gates,
//   positional staging with vmcnt(2) tile ledger, conflict-free
//   (r>>1)&3 image swizzle, XCD-chunked block swizzle, fused prepass.

typedef unsigned short u16;
typedef unsigned int u32;
typedef signed char s8;
typedef int v4i __attribute__((ext_vector_type(4)));

#define MDIM 16384
#define NDIM 4096
#define KDIM 4096

// ---------- helpers ----------

__device__ __forceinline__ float quant_wint(float w, float alpha) {
  // nearest of {3.5,4.0,4.5,5.0,5.5} to 4.5*(1+w*alpha); argmin tie -> lower level.
  float tv = 4.5f * (1.0f + w * alpha);
  float u = (tv - 3.5f) * 2.0f;
  float f = ceilf(u - 0.5f);
  f = fminf(fmaxf(f, 0.0f), 4.0f);
  return f - 2.0f;                  // Wint in {-2..2}; scale 1/(9*alpha) in epilogue
}

__device__ __forceinline__ void gld16(const void* g, void* l) {
  __builtin_amdgcn_global_load_lds(
      (const __attribute__((address_space(1))) void*)g,
      (__attribute__((address_space(3))) void*)l, 16, 0, 0);
}

__device__ __forceinline__ int q8(float x, float sinv) {
  float f = rintf(x * sinv);
  f = fminf(fmaxf(f, -127.0f), 127.0f);
  return (int)f;
}

// ---------- fused prepass: X rows then W rows, chunked+swizzled images ----------
// chunk(rowblk256,kblk64) = 16384B; image[r*64 + (c ^ (((r>>1)&3)<<4))]

__global__ __launch_bounds__(256) void quant_xw_kernel(
    const float4* __restrict__ X, const float4* __restrict__ W,
    const float* __restrict__ pAlpha,
    s8* __restrict__ Xq, s8* __restrict__ Wq, float* __restrict__ scales) {
  const int b = blockIdx.x;
  const int t = threadIdx.x;
  if (b < MDIM) {
    // ---- x row: per-row absmax scale -> i8 ----
    const int m = b;
    const float4* row = X + (size_t)m * 1024;
    float4 v0 = row[t * 4 + 0], v1 = row[t * 4 + 1], v2 = row[t * 4 + 2], v3 = row[t * 4 + 3];
    float vals[16] = {v0.x, v0.y, v0.z, v0.w, v1.x, v1.y, v1.z, v1.w,
                      v2.x, v2.y, v2.z, v2.w, v3.x, v3.y, v3.z, v3.w};
    float mx = 0.0f;
#pragma unroll
    for (int j = 0; j < 16; ++j) mx = fmaxf(mx, fabsf(vals[j]));
#pragma unroll
    for (int s = 1; s < 64; s <<= 1) mx = fmaxf(mx, __shfl_xor(mx, s));
    __shared__ float red[4];
    if ((t & 63) == 0) red[t >> 6] = mx;
    __syncthreads();
    float rmax = fmaxf(fmaxf(red[0], red[1]), fmaxf(red[2], red[3]));
    float sinv = rmax > 0.0f ? 127.0f / rmax : 0.0f;
    if (t == 0) scales[m] = rmax * (1.0f / 127.0f);
    u32 pk[4];
#pragma unroll
    for (int p = 0; p < 4; ++p) {
      u32 w = 0;
#pragma unroll
      for (int j = 0; j < 4; ++j)
        w |= ((u32)(unsigned char)(signed char)q8(vals[p * 4 + j], sinv)) << (8 * j);
      pk[p] = w;
    }
    size_t chunk = ((size_t)(m >> 8) * 64 + (size_t)(t >> 2)) * 16384;
    u32 off = (u32)((m & 255) * 64 + ((((t & 3) ^ ((m >> 1) & 3)) << 4)));
    *(uint4*)(Xq + chunk + off) = make_uint4(pk[0], pk[1], pk[2], pk[3]);
  } else {
    // ---- w row: quantize to Wint in {-2..2} ----
    const float alpha = pAlpha[0];
    const int n = b - MDIM;
    const float4* row = W + (size_t)n * 1024;
    float4 v0 = row[t * 4 + 0], v1 = row[t * 4 + 1], v2 = row[t * 4 + 2], v3 = row[t * 4 + 3];
    float vals[16] = {v0.x, v0.y, v0.z, v0.w, v1.x, v1.y, v1.z, v1.w,
                      v2.x, v2.y, v2.z, v2.w, v3.x, v3.y, v3.z, v3.w};
    u32 pk[4];
#pragma unroll
    for (int p = 0; p < 4; ++p) {
      u32 w = 0;
#pragma unroll
      for (int j = 0; j < 4; ++j) {
        int q = (int)quant_wint(vals[p * 4 + j], alpha);   // -2..2 exact
        w |= ((u32)(unsigned char)(signed char)q) << (8 * j);
      }
      pk[p] = w;
    }
    size_t chunk = ((size_t)(n >> 8) * 64 + (size_t)(t >> 2)) * 16384;
    u32 off = (u32)((n & 255) * 64 + ((((t & 3) ^ ((n >> 1) & 3)) << 4)));
    *(uint4*)(Wq + chunk + off) = make_uint4(pk[0], pk[1], pk[2], pk[3]);
  }
}

// ---------- main GEMM: 256x256, BK=64, i8, quad-A + cross-tile prefetch ----------

#define BM 256
#define BN 256
#define BK 64
#define NKT (KDIM / BK)   // 64

// LDS byte map: Abuf 0..3: q*16384 ; Bbuf 0: 65536, Bbuf 1: 81920  = 96 KiB
#define LA0 0
#define LA1 16384
#define LA2 32768
#define LA3 49152
#define LB0 65536
#define LB1 81920

__global__ __launch_bounds__(512, 2) void qgemm_kernel(
    const s8* __restrict__ Xq, const s8* __restrict__ Wq,
    const float* __restrict__ scales, const float* __restrict__ pAlpha,
    float* __restrict__ out) {
  __shared__ __align__(16) char sm8[98304];

  const int t512 = threadIdx.x;
  const int lane = t512 & 63;
  const int wave = t512 >> 6;
  const int wm = wave >> 2;      // 0..1
  const int wn = wave & 3;       // 0..3

  // XCD-chunked swizzle: nwg=1024, 8 XCDs, 128 per chunk
  const int bid = blockIdx.x;
  const int nid = (bid & 7) * 128 + (bid >> 3);
  const int m_idx = nid >> 4;    // 64 M-tiles
  const int n_idx = nid & 15;    // 16 N-tiles (consecutive nid share A panel)
  const int m0 = m_idx * BM, n0 = n_idx * BN;

  const float alpha = pAlpha[0];

  v4i acc[8][4] = {};
  v4i pa0, pa1, pa2, pa3;        // prefetched next-tile A-frags 0..3

  // read byte-offset within a 64B row: k-slot (lane>>4), XOR'd by (row>>1)&3
  const int koff = (((lane >> 4) ^ ((lane >> 1) & 3)) << 4);

#define AROW(MI) (wm * 64 + ((MI) >> 2) * 128 + ((MI)&3) * 16 + (lane & 15))
#define BROW(NJ) (wn * 32 + ((NJ) >> 1) * 128 + ((NJ)&1) * 16 + (lane & 15))
#define LDA(AB, MI) (*(const v4i*)(sm8 + (AB) + AROW(MI) * 64 + koff))
#define LDB(BB, NJ) (*(const v4i*)(sm8 + (BB) + BROW(NJ) * 64 + koff))

  // chunk bases (16 KiB per 256x64 operand tile; KT wraps, junk tail lands
  // only in buffers that are never read again)
#define GAC(KT) (Xq + ((size_t)m_idx * 64 + (size_t)((KT)&63)) * 16384)
#define GBC(KT) (Wq + ((size_t)n_idx * 64 + (size_t)((KT)&63)) * 16384)

  // stage one 8KB sweep (S=0/1) of a 16KB tile: 1 gld16/thread, linear dest
#define STAGE(GC, S, LB) do { \
    const s8* _g = (GC) + (S)*8192 + wave * 1024 + lane * 16; \
    gld16(_g, (void*)(sm8 + (LB) + (S)*8192 + wave * 1024)); \
  } while (0)

#define MFMA8(MI0, MI1, A0, A1) do { \
    acc[MI0][0] = __builtin_amdgcn_mfma_i32_16x16x64_i8(A0, b0, acc[MI0][0], 0, 0, 0); \
    acc[MI0][1] = __builtin_amdgcn_mfma_i32_16x16x64_i8(A0, b1, acc[MI0][1], 0, 0, 0); \
    acc[MI0][2] = __builtin_amdgcn_mfma_i32_16x16x64_i8(A0, b2, acc[MI0][2], 0, 0, 0); \
    acc[MI0][3] = __builtin_amdgcn_mfma_i32_16x16x64_i8(A0, b3, acc[MI0][3], 0, 0, 0); \
    acc[MI1][0] = __builtin_amdgcn_mfma_i32_16x16x64_i8(A1, b0, acc[MI1][0], 0, 0, 0); \
    acc[MI1][1] = __builtin_amdgcn_mfma_i32_16x16x64_i8(A1, b1, acc[MI1][1], 0, 0, 0); \
    acc[MI1][2] = __builtin_amdgcn_mfma_i32_16x16x64_i8(A1, b2, acc[MI1][2], 0, 0, 0); \
    acc[MI1][3] = __builtin_amdgcn_mfma_i32_16x16x64_i8(A1, b3, acc[MI1][3], 0, 0, 0); \
  } while (0)

#define SBAR __builtin_amdgcn_sched_barrier(0)
#define LGKM0 asm volatile("s_waitcnt lgkmcnt(0)" ::: "memory")

#define TILEGATE do { \
    SBAR; \
    asm volatile("s_waitcnt vmcnt(2)" ::: "memory"); \
    __builtin_amdgcn_s_barrier(); \
    SBAR; \
  } while (0)

  // one K-tile: ph0 fires clusters 0/1 from PREFETCHED regs (drain = 4 B
  // reads only); late phases prefetch next tile's A-frags 0..3 from ABN
  // (staged 3 tiles ago -> landed and barrier-synced). Stages positional:
  // B(t+1)s0, B(t+1)s1, A(t+3)s0, A(t+3)s1 -> vmcnt(2) leaves A(t+3).
#define KTILE(AB, ABN, BB, BBN, ASB, TT) do { \
    v4i b0 = LDB(BB, 0), b1 = LDB(BB, 1), b2 = LDB(BB, 2), b3 = LDB(BB, 3); \
    STAGE(GBC((TT) + 1), 0, BBN); \
    SBAR; LGKM0; SBAR; \
    __builtin_amdgcn_s_setprio(1); \
    MFMA8(0, 1, pa0, pa1); \
    __builtin_amdgcn_s_setprio(0); \
    SBAR; \
    v4i a4 = LDA(AB, 4), a5 = LDA(AB, 5); \
    STAGE(GBC((TT) + 1), 1, BBN); \
    SBAR; LGKM0; SBAR; \
    __builtin_amdgcn_s_setprio(1); \
    MFMA8(2, 3, pa2, pa3); \
    __builtin_amdgcn_s_setprio(0); \
    SBAR; \
    v4i a6 = LDA(AB, 6), a7 = LDA(AB, 7); \
    pa0 = LDA(ABN, 0); pa1 = LDA(ABN, 1); \
    STAGE(GAC((TT) + 3), 0, ASB); \
    SBAR; LGKM0; SBAR; \
    __builtin_amdgcn_s_setprio(1); \
    MFMA8(4, 5, a4, a5); \
    __builtin_amdgcn_s_setprio(0); \
    SBAR; \
    pa2 = LDA(ABN, 2); pa3 = LDA(ABN, 3); \
    STAGE(GAC((TT) + 3), 1, ASB); \
    SBAR; LGKM0; SBAR; \
    __builtin_amdgcn_s_setprio(1); \
    MFMA8(6, 7, a6, a7); \
    __builtin_amdgcn_s_setprio(0); \
    TILEGATE; \
  } while (0)

  // prologue: B(0)->Bb0, A(0)->LA0, A(1)->LA1, A(2)->LA2 (8 glds);
  // vmcnt(2) leaves A(2) in flight; B(0),A(0),A(1) landed. Then prefetch
  // tile 0's frags 0..3 from LA0 (ph0's LGKM0 covers the reads).
  STAGE(GBC(0), 0, LB0);
  STAGE(GBC(0), 1, LB0);
  STAGE(GAC(0), 0, LA0);
  STAGE(GAC(0), 1, LA0);
  STAGE(GAC(1), 0, LA1);
  STAGE(GAC(1), 1, LA1);
  STAGE(GAC(2), 0, LA2);
  STAGE(GAC(2), 1, LA2);
  asm volatile("s_waitcnt vmcnt(2)" ::: "memory");
  __builtin_amdgcn_s_barrier();
  SBAR;
  pa0 = LDA(LA0, 0); pa1 = LDA(LA0, 1);
  pa2 = LDA(LA0, 2); pa3 = LDA(LA0, 3);

#pragma unroll 1
  for (int t = 0; t < NKT; t += 4) {
    KTILE(LA0, LA1, LB0, LB1, LA3, t);        // reads A(t)  ; stages B(t+1), A(t+3)
    KTILE(LA1, LA2, LB1, LB0, LA0, t + 1);    // reads A(t+1); stages B(t+2), A(t+4)
    KTILE(LA2, LA3, LB0, LB1, LA1, t + 2);    // reads A(t+2); stages B(t+3), A(t+5)
    KTILE(LA3, LA0, LB1, LB0, LA2, t + 3);    // reads A(t+3); stages B(t+4), A(t+6)
  }

  // epilogue: out = acc_i32 * scales[row] / (9*alpha)
  const float inv9a = 1.0f / (9.0f * alpha);
#pragma unroll
  for (int mi = 0; mi < 8; ++mi) {
    int rbase = m0 + (mi >> 2) * 128 + wm * 64 + (mi & 3) * 16 + (lane >> 4) * 4;
    float s0 = scales[rbase + 0] * inv9a;
    float s1 = scales[rbase + 1] * inv9a;
    float s2 = scales[rbase + 2] * inv9a;
    float s3 = scales[rbase + 3] * inv9a;
#pragma unroll
    for (int nj = 0; nj < 4; ++nj) {
      int col = n0 + (nj >> 1) * 128 + wn * 32 + (nj & 1) * 16 + (lane & 15);
      out[(size_t)(rbase + 0) * NDIM + col] = (float)acc[mi][nj][0] * s0;
      out[(size_t)(rbase + 1) * NDIM + col] = (float)acc[mi][nj][1] * s1;
      out[(size_t)(rbase + 2) * NDIM + col] = (float)acc[mi][nj][2] * s2;
      out[(size_t)(rbase + 3) * NDIM + col] = (float)acc[mi][nj][3] * s3;
    }
  }
#undef KTILE
#undef TILEGATE
#undef LGKM0
#undef SBAR
#undef MFMA8
#undef STAGE
#undef GAC
#undef GBC
#undef LDA
#undef LDB
#undef AROW
#undef BROW
}

// ---------- fallback (ws too small): fp32 tiled GEMM, quant on the fly ----------

__global__ void fb_gemm_kernel(const float* __restrict__ X, const float* __restrict__ W,
                               const float* __restrict__ pAlpha, float* __restrict__ out) {
  __shared__ float As[64][17];
  __shared__ float Ws[64][17];
  const float alpha = pAlpha[0];
  const float scale = 1.0f / (9.0f * alpha);
  const int bm = blockIdx.x >> 6, bn = blockIdx.x & 63;
  const int t = threadIdx.x;
  const int tx = t & 15, ty = t >> 4;
  float acc[4][4] = {};
  for (int k0 = 0; k0 < KDIM; k0 += 16) {
    int r = t >> 2;
#pragma unroll
    for (int i = 0; i < 4; ++i) {
      int c = (t & 3) * 4 + i;
      As[r][c] = X[(size_t)(bm * 64 + r) * KDIM + k0 + c];
      float w = W[(size_t)(bn * 64 + r) * KDIM + k0 + c];
      Ws[r][c] = quant_wint(w, alpha) * scale;
    }
    __syncthreads();
#pragma unroll
    for (int kk = 0; kk < 16; ++kk)
#pragma unroll
      for (int i = 0; i < 4; ++i)
#pragma unroll
        for (int j = 0; j < 4; ++j)
          acc[i][j] += As[ty * 4 + i][kk] * Ws[tx * 4 + j][kk];
    __syncthreads();
  }
#pragma unroll
  for (int i = 0; i < 4; ++i)
#pragma unroll
    for (int j = 0; j < 4; ++j)
      out[(size_t)(bm * 64 + ty * 4 + i) * NDIM + bn * 64 + tx * 4 + j] = acc[i][j];
}

// ---------- launch ----------

extern "C" void kernel_launch(void* const* d_in, const int* in_sizes, int n_in,
                              void* d_out, int out_size, void* d_ws, size_t ws_size,
                              hipStream_t stream) {
  const float* x = (const float*)d_in[0];       // [16384,4096]
  const float* w = (const float*)d_in[1];       // [4096,4096]
  const float* alpha = (const float*)d_in[2];   // scalar
  float* out = (float*)d_out;

  const size_t XQ_BYTES = (size_t)MDIM * KDIM;              // 67.1 MB
  const size_t WQ_BYTES = (size_t)NDIM * KDIM;              // 16.8 MB
  const size_t SC_BYTES = (size_t)MDIM * 4;                 // 64 KB
  const size_t NEED = XQ_BYTES + WQ_BYTES + SC_BYTES;       // ~84 MB

  if (ws_size >= NEED) {
    s8* Xq = (s8*)d_ws;
    s8* Wq = (s8*)((char*)d_ws + XQ_BYTES);
    float* scales = (float*)((char*)d_ws + XQ_BYTES + WQ_BYTES);
    quant_xw_kernel<<<MDIM + NDIM, 256, 0, stream>>>(
        (const float4*)x, (const float4*)w, alpha, Xq, Wq, scales);
    qgemm_kernel<<<(MDIM / BM) * (NDIM / BN), 512, 0, stream>>>(
        Xq, Wq, scales, alpha, out);
  } else {
    fb_gemm_kernel<<<(MDIM / 64) * (NDIM / 64), 256, 0, stream>>>(x, w, alpha, out);
  }
}